// Round 1
// baseline (836.689 us; speedup 1.0000x reference)
//
#include <hip/hip_runtime.h>
#include <math.h>

// Softmax fwd + double-Jacobian-apply, fused single pass.
// s = softmax(mu, axis=1)
// jvp = s*(sigma - sum(s*sigma))
// out = s*(jvp - sum(s*jvp))
// With e = exp(mu - max), Z = sum(e):
//   dot1 = sum(e*sigma)/Z
//   dot2 = sum(s*jvp) = (sum(e^2*sigma) - dot1*sum(e^2)) / Z^2
//   out  = s*(s*(sigma - dot1) - dot2)

constexpr int C_DIM = 8192;
constexpr int BLOCK = 512;
constexpr int V4 = C_DIM / BLOCK / 4;  // float4s per thread = 4

__global__ __launch_bounds__(BLOCK) void softmax_djvp_kernel(
    const float* __restrict__ mu, const float* __restrict__ sigma,
    float* __restrict__ s_out, float* __restrict__ so_out) {
  const int row = blockIdx.x;
  const long base = (long)row * C_DIM;
  const float4* mu4 = (const float4*)(mu + base);
  const float4* sg4 = (const float4*)(sigma + base);
  float4* s4 = (float4*)(s_out + base);
  float4* o4 = (float4*)(so_out + base);

  const int t = threadIdx.x;
  const int wave = t >> 6;
  const int lane = t & 63;
  constexpr int NWAVES = BLOCK / 64;  // 8

  __shared__ float red_max[NWAVES];
  __shared__ float4 red_sum[NWAVES];

  // Load everything into registers (coalesced float4).
  float4 m[V4], g[V4];
#pragma unroll
  for (int k = 0; k < V4; ++k) {
    m[k] = mu4[t + BLOCK * k];
    g[k] = sg4[t + BLOCK * k];
  }

  // ---- reduction 1: row max of mu ----
  float mx = -INFINITY;
#pragma unroll
  for (int k = 0; k < V4; ++k) {
    mx = fmaxf(mx, fmaxf(fmaxf(m[k].x, m[k].y), fmaxf(m[k].z, m[k].w)));
  }
#pragma unroll
  for (int off = 32; off > 0; off >>= 1) mx = fmaxf(mx, __shfl_xor(mx, off, 64));
  if (lane == 0) red_max[wave] = mx;
  __syncthreads();
#pragma unroll
  for (int w = 0; w < NWAVES; ++w) mx = fmaxf(mx, red_max[w]);

  // ---- compute e, accumulate 4 sums: Z, sum(e*g), sum(e^2*g), sum(e^2) ----
  float z = 0.f, a = 0.f, b = 0.f, c = 0.f;
#pragma unroll
  for (int k = 0; k < V4; ++k) {
    float e0 = __expf(m[k].x - mx);
    float e1 = __expf(m[k].y - mx);
    float e2 = __expf(m[k].z - mx);
    float e3 = __expf(m[k].w - mx);
    m[k].x = e0; m[k].y = e1; m[k].z = e2; m[k].w = e3;  // overwrite mu with e
    z += (e0 + e1) + (e2 + e3);
    a += (e0 * g[k].x + e1 * g[k].y) + (e2 * g[k].z + e3 * g[k].w);
    b += (e0 * e0 * g[k].x + e1 * e1 * g[k].y) + (e2 * e2 * g[k].z + e3 * e3 * g[k].w);
    c += (e0 * e0 + e1 * e1) + (e2 * e2 + e3 * e3);
  }
#pragma unroll
  for (int off = 32; off > 0; off >>= 1) {
    z += __shfl_xor(z, off, 64);
    a += __shfl_xor(a, off, 64);
    b += __shfl_xor(b, off, 64);
    c += __shfl_xor(c, off, 64);
  }
  if (lane == 0) red_sum[wave] = make_float4(z, a, b, c);
  __syncthreads();
  z = 0.f; a = 0.f; b = 0.f; c = 0.f;
#pragma unroll
  for (int w = 0; w < NWAVES; ++w) {
    float4 r = red_sum[w];
    z += r.x; a += r.y; b += r.z; c += r.w;
  }

  const float rZ = 1.0f / z;
  const float dot1 = a * rZ;
  const float rZ2 = rZ * rZ;
  const float dot2 = rZ2 * (b - dot1 * c);

  // ---- epilogue: s = e*rZ; out = s*(s*(g - dot1) - dot2) ----
#pragma unroll
  for (int k = 0; k < V4; ++k) {
    float s0 = m[k].x * rZ, s1 = m[k].y * rZ, s2 = m[k].z * rZ, s3 = m[k].w * rZ;
    float4 sv = make_float4(s0, s1, s2, s3);
    float4 ov = make_float4(s0 * (s0 * (g[k].x - dot1) - dot2),
                            s1 * (s1 * (g[k].y - dot1) - dot2),
                            s2 * (s2 * (g[k].z - dot1) - dot2),
                            s3 * (s3 * (g[k].w - dot1) - dot2));
    s4[t + BLOCK * k] = sv;
    o4[t + BLOCK * k] = ov;
  }
}

extern "C" void kernel_launch(void* const* d_in, const int* in_sizes, int n_in,
                              void* d_out, int out_size, void* d_ws, size_t ws_size,
                              hipStream_t stream) {
  const float* mu = (const float*)d_in[0];
  const float* sigma = (const float*)d_in[1];
  float* out = (float*)d_out;
  const long n = (long)in_sizes[0];       // B*C
  const int rows = (int)(n / C_DIM);      // 8192
  float* s_out = out;                     // first output: s
  float* so_out = out + n;                // second output: sigma_out

  softmax_djvp_kernel<<<rows, BLOCK, 0, stream>>>(mu, sigma, s_out, so_out);
}